// Round 11
// baseline (150.778 us; speedup 1.0000x reference)
//
#include <hip/hip_runtime.h>

#define NTYPES 11
#define BLOCK  256
#define ITEMS  8
#define CHUNK  (BLOCK * ITEMS)   // 2048 atoms per block
#define MAXCH  32                // max scan chunks (B <= 2048)

// ---------------------------------------------------------------------------
// Kernel 1: per-block per-type histogram + 4-bit type packing.
// (byte-identical to the round-8 version, which passed)
// ---------------------------------------------------------------------------
__global__ __launch_bounds__(BLOCK) void hist_kernel(
    const int* __restrict__ types, int N, int B, int* __restrict__ bc,
    unsigned int* __restrict__ packed) {
  __shared__ int shCnt[NTYPES];
  const int tid = threadIdx.x;
  const int b = blockIdx.x;
  if (tid < NTYPES) shCnt[tid] = 0;
  __syncthreads();

  const int run = b * CHUNK + tid * ITEMS;
  int cnt[NTYPES];
#pragma unroll
  for (int t = 0; t < NTYPES; ++t) cnt[t] = 0;

  if (run < N) {
    const int4* p = (const int4*)(types + run);
    int4 a0 = p[0], a1 = p[1];
    int ty[ITEMS] = {a0.x, a0.y, a0.z, a0.w, a1.x, a1.y, a1.z, a1.w};
    unsigned int pk = 0;
#pragma unroll
    for (int k = 0; k < ITEMS; ++k) pk |= ((unsigned int)ty[k]) << (4 * k);
    packed[b * BLOCK + tid] = pk;
#pragma unroll
    for (int k = 0; k < ITEMS; ++k) {
#pragma unroll
      for (int t = 0; t < NTYPES; ++t) cnt[t] += (ty[k] == t) ? 1 : 0;
    }
  }

  const int lane = tid & 63;
#pragma unroll
  for (int t = 0; t < NTYPES; ++t) {
    int v = cnt[t];
    for (int o = 32; o >= 1; o >>= 1) v += __shfl_down(v, o);
    if (lane == 0) atomicAdd(&shCnt[t], v);
  }
  __syncthreads();
  if (tid < NTYPES) bc[tid * B + b] = shCnt[tid];
}

// ---------------------------------------------------------------------------
// Kernel 2: one block, 11 waves; wave t scans type t's block-counts.
// (byte-identical to the r0 baseline, which passed repeatedly)
// ---------------------------------------------------------------------------
__global__ __launch_bounds__(NTYPES * 64) void scan_kernel(
    const int* __restrict__ bc, int B, int* __restrict__ scanOut,
    int* __restrict__ offs, float* __restrict__ outTail) {
  __shared__ int totals[NTYPES];
  const int lane = threadIdx.x & 63;
  const int t = threadIdx.x >> 6;
  const int nch = (B + 63) >> 6;

  int x[MAXCH];
#pragma unroll
  for (int c = 0; c < MAXCH; ++c) {
    const int idx = c * 64 + lane;
    x[c] = (c < nch && idx < B) ? bc[t * B + idx] : 0;
  }

  int carry = 0;
#pragma unroll
  for (int c = 0; c < MAXCH; ++c) {
    if (c >= nch) break;
    int incl = x[c];
#pragma unroll
    for (int o = 1; o < 64; o <<= 1) {
      int v = __shfl_up(incl, o);
      if (lane >= o) incl += v;
    }
    incl += carry;
    const int idx = c * 64 + lane;
    if (idx < B) scanOut[t * B + idx] = incl - x[c];
    carry = __shfl(incl, 63);
  }
  if (lane == 0) totals[t] = carry;
  __syncthreads();

  if (threadIdx.x == 0) {
    int off = 0;
    for (int u = 0; u < NTYPES; ++u) {
      const int c = totals[u];
      offs[u] = off;
      outTail[u] = (float)c;            // counts (as float values)
      outTail[NTYPES + u] = (float)off; // offsets (as float values)
      off += c;
    }
  }
}

// ---------------------------------------------------------------------------
// Kernel 3: stable scatter via u16 PERMUTATION + gather copy-out.
// Instead of staging 24 KB of coords through LDS (write+read round-trip),
// phase 1 stores only perm[slot] = local atom index (4 KB u16). Phase 2
// gathers coords from global: stability makes perm monotone within each type
// segment, so gathers walk the block's 24 KB coords window near-sequentially
// (L1/L2/L3 absorb line amplification; HBM reads each byte once). Stores are
// the same coalesced pattern as r0's proven copy-out.
// LDS 24.4 KB -> 4.5 KB: residency 6 -> 8 blocks/CU (32-wave cap, 100%).
// ---------------------------------------------------------------------------
__global__ __launch_bounds__(BLOCK) void scatter_kernel(
    const float* __restrict__ coords, const unsigned int* __restrict__ packed,
    const int* __restrict__ scanOut, const int* __restrict__ offs, int N,
    int B, float* __restrict__ out) {
  __shared__ unsigned short perm[CHUNK];  // 4 KB: slot -> local atom index
  __shared__ int wtot[NTYPES][4];         // per-wave inclusive totals
  __shared__ int shOff[NTYPES + 1];       // local bucket offsets (exclusive)
  __shared__ int shDelta[NTYPES];         // 3*(globalBase[t] - shOff[t])

  const int tid = threadIdx.x;
  const int b = blockIdx.x;
  const int lane = tid & 63;
  const int wave = tid >> 6;
  const int run = b * CHUNK + tid * ITEMS;
  const bool active = (run < N);

  int ty[ITEMS];
  int cnt[NTYPES];
#pragma unroll
  for (int t = 0; t < NTYPES; ++t) cnt[t] = 0;
#pragma unroll
  for (int k = 0; k < ITEMS; ++k) ty[k] = -1;

  if (active) {
    const unsigned int pk = packed[b * BLOCK + tid];
#pragma unroll
    for (int k = 0; k < ITEMS; ++k) ty[k] = (int)((pk >> (4 * k)) & 0xFu);
#pragma unroll
    for (int k = 0; k < ITEMS; ++k) {
#pragma unroll
      for (int t = 0; t < NTYPES; ++t) cnt[t] += (ty[k] == t) ? 1 : 0;
    }
  }

  // Wave-level stable exclusive scan per type (unpacked, as in r0).
  int rank[NTYPES];
#pragma unroll
  for (int t = 0; t < NTYPES; ++t) {
    int incl = cnt[t];
#pragma unroll
    for (int o = 1; o < 64; o <<= 1) {
      int v = __shfl_up(incl, o);
      if (lane >= o) incl += v;
    }
    if (lane == 63) wtot[t][wave] = incl;
    rank[t] = incl - cnt[t];  // exclusive within wave
  }
  __syncthreads();

  // Local bucket offsets + global deltas (threads 0..NTYPES-1).
  if (tid < NTYPES) {
    int loc = 0;
    for (int u = 0; u < tid; ++u)
      loc += wtot[u][0] + wtot[u][1] + wtot[u][2] + wtot[u][3];
    shOff[tid] = loc;
    shDelta[tid] = 3 * (offs[tid] + scanOut[tid * B + b] - loc);
    if (tid == NTYPES - 1) {
      shOff[NTYPES] =
          loc + wtot[tid][0] + wtot[tid][1] + wtot[tid][2] + wtot[tid][3];
    }
  }
  __syncthreads();

  // Finalize local ranks: bucket base + wave base + lane-exclusive.
#pragma unroll
  for (int t = 0; t < NTYPES; ++t) {
    int wb = 0;
#pragma unroll
    for (int w = 0; w < 3; ++w) wb += (w < wave) ? wtot[t][w] : 0;
    rank[t] += wb + shOff[t];
  }

  // Write permutation: slot -> local atom index (u16, 2-way-per-dword max
  // aliasing on LDS banks = free per bank rules).
  if (active) {
#pragma unroll
    for (int k = 0; k < ITEMS; ++k) {
      const int t0 = ty[k];
      int slot = 0;
#pragma unroll
      for (int t = 0; t < NTYPES; ++t) {
        if (t0 == t) {
          slot = rank[t];
          rank[t] += 1;
        }
      }
      perm[slot] = (unsigned short)(tid * ITEMS + k);
    }
  }
  __syncthreads();

  // Gather copy-out: slot s takes coords of atom perm[s] (near-sequential
  // within each type segment) to out[3*s + delta3[type(s)]] (coalesced).
  const int total = shOff[NTYPES];
  int offr[NTYPES];
  int dlt[NTYPES];
#pragma unroll
  for (int t = 0; t < NTYPES; ++t) {
    offr[t] = shOff[t];
    dlt[t] = shDelta[t];
  }
  const float* cbase = coords + (size_t)b * CHUNK * 3;
#pragma unroll
  for (int k = 0; k < ITEMS; ++k) {
    const int s = k * BLOCK + tid;
    if (s < total) {
      const int li = (int)perm[s];
      int d = dlt[0];
#pragma unroll
      for (int t = 1; t < NTYPES; ++t) d = (s >= offr[t]) ? dlt[t] : d;
      const int src = 3 * li;
      const int dst = 3 * s + d;
      out[dst + 0] = cbase[src + 0];
      out[dst + 1] = cbase[src + 1];
      out[dst + 2] = cbase[src + 2];
    }
  }
}

extern "C" void kernel_launch(void* const* d_in, const int* in_sizes, int n_in,
                              void* d_out, int out_size, void* d_ws,
                              size_t ws_size, hipStream_t stream) {
  const float* coords = (const float*)d_in[0];
  const int* types = (const int*)d_in[1];
  const int N = in_sizes[1];              // 4,000,000 atoms
  const int B = (N + CHUNK - 1) / CHUNK;  // 1954 blocks

  int* bc = (int*)d_ws;                        // [NTYPES * B]
  int* scanOut = bc + NTYPES * B;              // [NTYPES * B]
  int* offs = scanOut + NTYPES * B;            // [NTYPES]
  unsigned int* packed = (unsigned int*)(offs + NTYPES + 1);  // [B * BLOCK]
  float* out = (float*)d_out;
  float* outTail = out + (size_t)3 * N;  // counts then offsets, as floats

  hist_kernel<<<B, BLOCK, 0, stream>>>(types, N, B, bc, packed);
  scan_kernel<<<1, NTYPES * 64, 0, stream>>>(bc, B, scanOut, offs, outTail);
  scatter_kernel<<<B, BLOCK, 0, stream>>>(coords, packed, scanOut, offs, N, B,
                                          out);
}

// Round 12
// 138.744 us; speedup vs baseline: 1.0867x; 1.0867x over previous
//
#include <hip/hip_runtime.h>

#define NTYPES 11
#define BLOCK  256
#define ITEMS  8
#define CHUNK  (BLOCK * ITEMS)   // 2048 atoms per block
#define MAXCH  32                // max scan chunks (B <= 2048)

// ---------------------------------------------------------------------------
// Kernel 1: histogram + per-atom SLOT computation.
// Computes each atom's stable local bucket slot (the rank logic formerly in
// scatter) and writes it as u16 (8 MB, coalesced 16 B/thread). The shfl
// REDUCE of the old hist becomes a shfl SCAN -- same instruction count; the
// extra wtot/shOff phases live here, in the single-load-phase kernel with
// latency slack, instead of in the 4-phase scatter. bc output unchanged.
// ---------------------------------------------------------------------------
__global__ __launch_bounds__(BLOCK) void hist_kernel(
    const int* __restrict__ types, int N, int B, int* __restrict__ bc,
    unsigned short* __restrict__ slots) {
  __shared__ int wtot[NTYPES][4];  // per-wave inclusive totals
  __shared__ int shOff[NTYPES];    // local bucket offsets (exclusive)
  const int tid = threadIdx.x;
  const int b = blockIdx.x;
  const int lane = tid & 63;
  const int wave = tid >> 6;
  const int run = b * CHUNK + tid * ITEMS;
  const bool active = (run < N);

  int ty[ITEMS];
  int cnt[NTYPES];
#pragma unroll
  for (int t = 0; t < NTYPES; ++t) cnt[t] = 0;
#pragma unroll
  for (int k = 0; k < ITEMS; ++k) ty[k] = -1;

  if (active) {
    const int4* p = (const int4*)(types + run);
    int4 a0 = p[0], a1 = p[1];
    int tt[ITEMS] = {a0.x, a0.y, a0.z, a0.w, a1.x, a1.y, a1.z, a1.w};
#pragma unroll
    for (int k = 0; k < ITEMS; ++k) ty[k] = tt[k];
#pragma unroll
    for (int k = 0; k < ITEMS; ++k) {
#pragma unroll
      for (int t = 0; t < NTYPES; ++t) cnt[t] += (ty[k] == t) ? 1 : 0;
    }
  }

  // Wave-level stable exclusive scan per type (r0's proven pattern).
  int rank[NTYPES];
#pragma unroll
  for (int t = 0; t < NTYPES; ++t) {
    int incl = cnt[t];
#pragma unroll
    for (int o = 1; o < 64; o <<= 1) {
      int v = __shfl_up(incl, o);
      if (lane >= o) incl += v;
    }
    if (lane == 63) wtot[t][wave] = incl;
    rank[t] = incl - cnt[t];  // exclusive within wave
  }
  __syncthreads();

  // Local bucket offsets + per-block type counts (threads 0..NTYPES-1).
  if (tid < NTYPES) {
    int loc = 0;
    for (int u = 0; u < tid; ++u)
      loc += wtot[u][0] + wtot[u][1] + wtot[u][2] + wtot[u][3];
    shOff[tid] = loc;
    bc[tid * B + b] =
        wtot[tid][0] + wtot[tid][1] + wtot[tid][2] + wtot[tid][3];
  }
  __syncthreads();

  // Finalize local ranks: bucket base + wave base + lane-exclusive.
#pragma unroll
  for (int t = 0; t < NTYPES; ++t) {
    int wb = 0;
#pragma unroll
    for (int w = 0; w < 3; ++w) wb += (w < wave) ? wtot[t][w] : 0;
    rank[t] += wb + shOff[t];
  }

  // Per-atom slots, packed 8 x u16 -> one 16 B coalesced store.
  if (active) {
    unsigned short sl[ITEMS];
#pragma unroll
    for (int k = 0; k < ITEMS; ++k) {
      const int t0 = ty[k];
      int slot = 0;
#pragma unroll
      for (int t = 0; t < NTYPES; ++t) {
        if (t0 == t) {
          slot = rank[t];
          rank[t] += 1;
        }
      }
      sl[k] = (unsigned short)slot;
    }
    int4 sv;
    sv.x = (int)sl[0] | ((int)sl[1] << 16);
    sv.y = (int)sl[2] | ((int)sl[3] << 16);
    sv.z = (int)sl[4] | ((int)sl[5] << 16);
    sv.w = (int)sl[6] | ((int)sl[7] << 16);
    *(int4*)(slots + run) = sv;  // run*2 is 16 B aligned
  }
}

// ---------------------------------------------------------------------------
// Kernel 2: one block, 11 waves; wave t scans type t's block-counts.
// (byte-identical to the r0 baseline, which passed repeatedly)
// ---------------------------------------------------------------------------
__global__ __launch_bounds__(NTYPES * 64) void scan_kernel(
    const int* __restrict__ bc, int B, int* __restrict__ scanOut,
    int* __restrict__ offs, float* __restrict__ outTail) {
  __shared__ int totals[NTYPES];
  const int lane = threadIdx.x & 63;
  const int t = threadIdx.x >> 6;
  const int nch = (B + 63) >> 6;

  int x[MAXCH];
#pragma unroll
  for (int c = 0; c < MAXCH; ++c) {
    const int idx = c * 64 + lane;
    x[c] = (c < nch && idx < B) ? bc[t * B + idx] : 0;
  }

  int carry = 0;
#pragma unroll
  for (int c = 0; c < MAXCH; ++c) {
    if (c >= nch) break;
    int incl = x[c];
#pragma unroll
    for (int o = 1; o < 64; o <<= 1) {
      int v = __shfl_up(incl, o);
      if (lane >= o) incl += v;
    }
    incl += carry;
    const int idx = c * 64 + lane;
    if (idx < B) scanOut[t * B + idx] = incl - x[c];
    carry = __shfl(incl, 63);
  }
  if (lane == 0) totals[t] = carry;
  __syncthreads();

  if (threadIdx.x == 0) {
    int off = 0;
    for (int u = 0; u < NTYPES; ++u) {
      const int c = totals[u];
      offs[u] = off;
      outTail[u] = (float)c;            // counts (as float values)
      outTail[NTYPES + u] = (float)off; // offsets (as float values)
      off += c;
    }
  }
}

// ---------------------------------------------------------------------------
// Kernel 3: SINGLE-BARRIER scatter -- pure data movement.
// Slots are precomputed, so there is no count, no shfl scan, no wtot phase:
// {tid<11: shOff/shDelta from bc/scanOut/offs (66 pipelined L2-hot loads,
//  no barrier needed)} runs concurrently with {all threads: load slots (16B)
// + coords (96B), write coords into LDS by slot}. ONE barrier, then r8's
// proven float4-window copy-out. Was: 4 barriers + ~300 VALU + 66 DS ops.
// ---------------------------------------------------------------------------
__global__ __launch_bounds__(BLOCK) void scatter_kernel(
    const float* __restrict__ coords, const unsigned short* __restrict__ slots,
    const int* __restrict__ bc, const int* __restrict__ scanOut,
    const int* __restrict__ offs, int N, int B, float* __restrict__ out) {
  __shared__ float shC[CHUNK * 3];      // 24 KB type-sorted coords
  __shared__ int shOff[NTYPES + 1];     // local bucket offsets (exclusive)
  __shared__ int shDelta[NTYPES];       // 3*(globalBase[t] - shOff[t])

  const int tid = threadIdx.x;
  const int b = blockIdx.x;
  const int run = b * CHUNK + tid * ITEMS;
  const bool active = (run < N);

  // Meta phase: each of threads 0..10 independently sums bc[u*B+b] for u<tid
  // (<=10 L2-hot loads, latency-pipelined) -- no inter-thread dependency, so
  // no barrier before the main one.
  if (tid < NTYPES) {
    int loc = 0;
    for (int u = 0; u < tid; ++u) loc += bc[u * B + b];
    shOff[tid] = loc;
    shDelta[tid] = 3 * (offs[tid] + scanOut[tid * B + b] - loc);
    if (tid == NTYPES - 1) shOff[NTYPES] = loc + bc[tid * B + b];
  }

  // Data phase (concurrent with meta): place coords into LDS by slot.
  if (active) {
    const int4 sv = *(const int4*)(slots + run);
    int sl[ITEMS] = {sv.x & 0xFFFF, (sv.x >> 16) & 0xFFFF,
                     sv.y & 0xFFFF, (sv.y >> 16) & 0xFFFF,
                     sv.z & 0xFFFF, (sv.z >> 16) & 0xFFFF,
                     sv.w & 0xFFFF, (sv.w >> 16) & 0xFFFF};
    const float4* cp = (const float4*)(coords + (size_t)run * 3);
    float c[ITEMS * 3];
#pragma unroll
    for (int q = 0; q < (ITEMS * 3) / 4; ++q) {
      float4 v = cp[q];
      c[4 * q + 0] = v.x;
      c[4 * q + 1] = v.y;
      c[4 * q + 2] = v.z;
      c[4 * q + 3] = v.w;
    }
#pragma unroll
    for (int k = 0; k < ITEMS; ++k) {
      const int s = sl[k];
      shC[3 * s + 0] = c[3 * k + 0];
      shC[3 * s + 1] = c[3 * k + 1];
      shC[3 * s + 2] = c[3 * k + 2];
    }
  }
  __syncthreads();  // the ONLY barrier

  // Copy-out over 4-float windows (r8's proven code; total3 multiple of 4).
  const int total3 = 3 * shOff[NTYPES];
  int offr3[NTYPES];
  int dlt[NTYPES];
#pragma unroll
  for (int t = 0; t < NTYPES; ++t) {
    offr3[t] = 3 * shOff[t];
    dlt[t] = shDelta[t];
  }
  const float4* shC4 = (const float4*)shC;
#pragma unroll
  for (int k = 0; k < (ITEMS * 3) / 4; ++k) {
    const int w = k * BLOCK + tid;
    const int j0 = 4 * w;
    if (j0 < total3) {
      const float4 v = shC4[w];
      int d0 = dlt[0], d3 = dlt[0];
#pragma unroll
      for (int t = 1; t < NTYPES; ++t) {
        d0 = (j0 >= offr3[t]) ? dlt[t] : d0;
        d3 = (j0 + 3 >= offr3[t]) ? dlt[t] : d3;
      }
      if (d0 == d3) {
        out[j0 + d0 + 0] = v.x;
        out[j0 + d0 + 1] = v.y;
        out[j0 + d0 + 2] = v.z;
        out[j0 + d0 + 3] = v.w;
      } else {  // rare: window crosses a type boundary (<=10 windows/block)
        int d1 = dlt[0], d2 = dlt[0];
#pragma unroll
        for (int t = 1; t < NTYPES; ++t) {
          d1 = (j0 + 1 >= offr3[t]) ? dlt[t] : d1;
          d2 = (j0 + 2 >= offr3[t]) ? dlt[t] : d2;
        }
        out[j0 + d0 + 0] = v.x;
        out[j0 + d1 + 1] = v.y;
        out[j0 + d2 + 2] = v.z;
        out[j0 + d3 + 3] = v.w;
      }
    }
  }
}

extern "C" void kernel_launch(void* const* d_in, const int* in_sizes, int n_in,
                              void* d_out, int out_size, void* d_ws,
                              size_t ws_size, hipStream_t stream) {
  const float* coords = (const float*)d_in[0];
  const int* types = (const int*)d_in[1];
  const int N = in_sizes[1];              // 4,000,000 atoms
  const int B = (N + CHUNK - 1) / CHUNK;  // 1954 blocks

  int* bc = (int*)d_ws;                        // [NTYPES * B]
  int* scanOut = bc + NTYPES * B;              // [NTYPES * B]
  int* offs = scanOut + NTYPES * B;            // [NTYPES]
  unsigned short* slots = (unsigned short*)(offs + NTYPES + 1);  // [B*CHUNK]
  float* out = (float*)d_out;
  float* outTail = out + (size_t)3 * N;  // counts then offsets, as floats

  hist_kernel<<<B, BLOCK, 0, stream>>>(types, N, B, bc, slots);
  scan_kernel<<<1, NTYPES * 64, 0, stream>>>(bc, B, scanOut, offs, outTail);
  scatter_kernel<<<B, BLOCK, 0, stream>>>(coords, slots, bc, scanOut, offs, N,
                                          B, out);
}